// Round 5
// baseline (409.444 us; speedup 1.0000x reference)
//
#include <hip/hip_runtime.h>
#include <hip/hip_bf16.h>
#include <cstdint>
#include <cstddef>

// ---------------------------------------------------------------------------
// LRU layer (fp32 I/O): h = scan( (x W_in^T + b_in)*gamma, lambda, mask )
//                       out = LN( Re(h W_out^T + b_out) + x )
// B=8 L=2048 D=512 H=1024. GEMMs: bf16 MFMA fp32-accum, fragments loaded
// DIRECTLY global->register (no LDS, no barriers: each lane's 16B fragment
// is 1/4 of a 64B line; per-instr segment count equals the coalesced ideal).
// Register double-buffer gives one full K-iteration of load slack.
// ---------------------------------------------------------------------------

typedef unsigned short u16;
typedef __attribute__((ext_vector_type(8))) short bf16x8;   // 8 bf16 = 4 VGPRs
typedef __attribute__((ext_vector_type(4))) float f32x4;

#define B_    8
#define L_    2048
#define D_    512
#define H_    1024
#define M_    (B_ * L_)      // 16384 rows
#define SEG_  64             // scan segments (512 blocks)
#define T_    (L_ / SEG_)    // 32 steps/segment

__device__ __forceinline__ float b2f(u16 u) {
  union { unsigned int i; float f; } v; v.i = ((unsigned int)u) << 16; return v.f;
}
__device__ __forceinline__ u16 f2b(float f) {
  union { float f; unsigned int i; } v; v.f = f;
  unsigned int x = v.i;
  return (u16)((x + 0x7fffu + ((x >> 16) & 1u)) >> 16);   // RNE
}

// ---------------------------------------------------------------------------
// fp32 -> bf16 elementwise, 4 elems/thread (n4 = n/4 float4 groups)
// ---------------------------------------------------------------------------
__global__ __launch_bounds__(256) void conv_f32_bf16(
    const float* __restrict__ in, u16* __restrict__ out, int n4)
{
  int i = blockIdx.x * 256 + threadIdx.x;
  if (i < n4) {
    float4 v = ((const float4*)in)[i];
    ushort4 o;
    o.x = f2b(v.x); o.y = f2b(v.y); o.z = f2b(v.z); o.w = f2b(v.w);
    ((ushort4*)out)[i] = o;
  }
}

// Weight prep: winb rows pre-scaled by gamma:
//   winb[n][k] = bf16(W_in[n][k] * gamma[n&1023]),  rows [re(1024) | im(1024)]
//   wcat[d][c]=W_out_re[d][c], wcat[d][1024+c]=-W_out_im[d][c]
//   bb[n] = b_in[n] * gamma[n&1023]   (fp32, 2048)
__global__ __launch_bounds__(256) void prep_weights(
    const float* __restrict__ wire, const float* __restrict__ wiim,
    const float* __restrict__ wore, const float* __restrict__ woim,
    const float* __restrict__ bire, const float* __restrict__ biim,
    const float* __restrict__ params,
    u16* __restrict__ winb, u16* __restrict__ wcat, float* __restrict__ bb)
{
  int i = blockIdx.x * 256 + threadIdx.x;        // 0 .. 524287
  float g = expf(params[2 * H_ + (i >> 9)]);     // gamma for W_in row i>>9
  winb[i]           = f2b(wire[i] * g);
  winb[H_ * D_ + i] = f2b(wiim[i] * g);
  int d = i >> 10, c = i & 1023;
  wcat[(size_t)d * 2048 + c]        = f2b(wore[i]);
  wcat[(size_t)d * 2048 + 1024 + c] = f2b(-woim[i]);
  if (i < 2048) {
    float gb = expf(params[2 * H_ + (i & (H_ - 1))]);
    bb[i] = ((i < 1024) ? bire[i] : biim[i - 1024]) * gb;
  }
}

// ---------------------------------------------------------------------------
// gemm_direct: C(M x N) = A(M x K) * B(N x K)^T.  128x128 block tile, 4 waves
// in 2x2 (64x64 each, 4x4 of 16x16x32 MFMA).  NO LDS/barriers: fragments are
// 16B global loads straight into VGPRs (4 lanes q=0..3 cover one 64B line per
// row); register double-buffer prefetches iteration k+1 during MFMAs of k.
// Operand-swapped MFMA: D row (q*4+i) = n, col (r) = m -> 4-consecutive-n
// packed stores.  Grid: blockIdx.x = m-block (fast) -> A-sharers on one XCD.
// MODE 0: out bf16, val = acc + p0[n];  MODE 1: out fp32, val = acc + p0[n].
// ---------------------------------------------------------------------------
template <int MODE>
__global__ __launch_bounds__(256, 3) void gemm_direct(
    const u16* __restrict__ A, const u16* __restrict__ Bp, int K,
    void* __restrict__ outp, int ldc, const float* __restrict__ p0)
{
  const int tid  = threadIdx.x;
  const int lane = tid & 63;
  const int wave = tid >> 6;
  const int wm = wave >> 1, wn = wave & 1;           // 2x2 wave grid
  const int m0 = blockIdx.x * 128;                   // m on fast axis
  const int n0 = blockIdx.y * 128;

  const int q = lane >> 4;       // quad 0..3 -> k-offset q*8
  const int r = lane & 15;       // row index within 16

  const u16* aptr = A  + (size_t)(m0 + wm * 64 + r) * K + q * 8;
  const u16* bptr = Bp + (size_t)(n0 + wn * 64 + r) * K + q * 8;
  const size_t strideA = (size_t)16 * K;             // 16 rows per tile step

  f32x4 acc[4][4];
#pragma unroll
  for (int i = 0; i < 4; ++i)
#pragma unroll
    for (int j = 0; j < 4; ++j) { f32x4 z = {0.f, 0.f, 0.f, 0.f}; acc[i][j] = z; }

  bf16x8 ca[4], cb[4], na[4], nb[4];
#pragma unroll
  for (int t = 0; t < 4; ++t) {
    ca[t] = *(const bf16x8*)(aptr + t * strideA);
    cb[t] = *(const bf16x8*)(bptr + t * strideA);
  }

#pragma unroll 2
  for (int k0 = 0; k0 < K; k0 += 32) {
    if (k0 + 32 < K) {
#pragma unroll
      for (int t = 0; t < 4; ++t) {
        na[t] = *(const bf16x8*)(aptr + t * strideA + k0 + 32);
        nb[t] = *(const bf16x8*)(bptr + t * strideA + k0 + 32);
      }
    }
#pragma unroll
    for (int mt = 0; mt < 4; ++mt)
#pragma unroll
      for (int nt = 0; nt < 4; ++nt)
        acc[mt][nt] = __builtin_amdgcn_mfma_f32_16x16x32_bf16(
            cb[nt], ca[mt], acc[mt][nt], 0, 0, 0);
#pragma unroll
    for (int t = 0; t < 4; ++t) { ca[t] = na[t]; cb[t] = nb[t]; }
  }

  // epilogue: thread holds n = nb4..nb4+3 (contiguous) for each of 16 tiles
#pragma unroll
  for (int nt = 0; nt < 4; ++nt) {
    const int nb4 = n0 + wn * 64 + nt * 16 + q * 4;
    const float4 b4 = *(const float4*)&p0[nb4];
#pragma unroll
    for (int mt = 0; mt < 4; ++mt) {
      const int mg = m0 + wm * 64 + mt * 16 + r;
      if (MODE == 0) {
        ushort4 o;
        o.x = f2b(acc[mt][nt][0] + b4.x);
        o.y = f2b(acc[mt][nt][1] + b4.y);
        o.z = f2b(acc[mt][nt][2] + b4.z);
        o.w = f2b(acc[mt][nt][3] + b4.w);
        *(ushort4*)&((u16*)outp)[(size_t)mg * ldc + nb4] = o;
      } else {
        float4 o;
        o.x = acc[mt][nt][0] + b4.x;
        o.y = acc[mt][nt][1] + b4.y;
        o.z = acc[mt][nt][2] + b4.z;
        o.w = acc[mt][nt][3] + b4.w;
        *(float4*)&((float*)outp)[(size_t)mg * ldc + nb4] = o;
      }
    }
  }
}

// ---------------------------------------------------------------------------
// Scan pass 1 (read-only): segment-final state (zero init) + mask product.
// 8-row chunks, double-buffered loads.  h_t = x_t + lambda*m[t-1]*h_{t-1}.
// ---------------------------------------------------------------------------
__global__ __launch_bounds__(256) void scan_fin(
    const u16* __restrict__ h, const float* __restrict__ mask,
    const float* __restrict__ params, float2* __restrict__ segfin,
    float* __restrict__ prodm)
{
  const int s = blockIdx.x, b = blockIdx.y;
  const int c4 = threadIdx.x * 4;
  float lr[4], li[4];
#pragma unroll
  for (int j = 0; j < 4; ++j) {
    int c = c4 + j;
    float nu = expf(params[c]);
    float th = expf(params[H_ + c]);
    float mg = expf(-nu);
    lr[j] = mg * cosf(th);
    li[j] = mg * sinf(th);
  }
  const int t0 = s * T_;
  const u16* p = h + (size_t)(b * L_ + t0) * (2 * H_) + c4;
  const float* mp = mask + b * L_ + t0;
  float fac0;                 // block-uniform: no OOB speculative load
  if (t0 == 0) fac0 = 0.f; else fac0 = mask[b * L_ + t0 - 1];

  ushort4 bre[2][8], bim[2][8];
#pragma unroll
  for (int j = 0; j < 8; ++j) {
    bre[0][j] = *(const ushort4*)(p + (size_t)j * 2 * H_);
    bim[0][j] = *(const ushort4*)(p + (size_t)j * 2 * H_ + H_);
  }
  float sr[4] = {0, 0, 0, 0}, si[4] = {0, 0, 0, 0};
  float pm = 1.f;
#pragma unroll
  for (int ch = 0; ch < T_ / 8; ++ch) {
    const int cur = ch & 1, nxt = cur ^ 1;
    if (ch < T_ / 8 - 1) {
      const u16* pn = p + (size_t)(ch + 1) * 8 * 2 * H_;
#pragma unroll
      for (int j = 0; j < 8; ++j) {
        bre[nxt][j] = *(const ushort4*)(pn + (size_t)j * 2 * H_);
        bim[nxt][j] = *(const ushort4*)(pn + (size_t)j * 2 * H_ + H_);
      }
    }
#pragma unroll
    for (int j = 0; j < 8; ++j) {
      int i = ch * 8 + j;
      float fac = (i == 0) ? fac0 : mp[i - 1];
      pm *= fac;
      u16 rr[4], ii[4];
      *(ushort4*)rr = bre[cur][j]; *(ushort4*)ii = bim[cur][j];
#pragma unroll
      for (int k = 0; k < 4; ++k) {
        float ar = fac * sr[k], ai = fac * si[k];
        sr[k] = b2f(rr[k]) + lr[k] * ar - li[k] * ai;
        si[k] = b2f(ii[k]) + lr[k] * ai + li[k] * ar;
      }
    }
  }
#pragma unroll
  for (int j = 0; j < 4; ++j)
    segfin[(size_t)(b * SEG_ + s) * H_ + c4 + j] = make_float2(sr[j], si[j]);
  if (threadIdx.x == 0) prodm[b * SEG_ + s] = pm;
}

// ---------------------------------------------------------------------------
// Scan pass 2: carries[s] = state entering segment s.
// carry_{s+1} = fin_s + prodm_s * lambda^T * carry_s; lambda^T via 5
// squarings (T=32).  Next-iter loads prefetched past the dependent update.
// ---------------------------------------------------------------------------
__global__ __launch_bounds__(256) void scan_carry(
    const float2* __restrict__ segfin, const float* __restrict__ prodm,
    const float* __restrict__ params, float2* __restrict__ carries)
{
  int idx = blockIdx.x * 256 + threadIdx.x;   // 0..8191
  int b = idx >> 10, c = idx & 1023;
  float nu = expf(params[c]);
  float th = expf(params[H_ + c]);
  float mg = expf(-nu);
  float ltr = mg * cosf(th), lti = mg * sinf(th);
#pragma unroll
  for (int sq = 0; sq < 5; ++sq) {            // lambda^(2^5) = lambda^T, T=32
    float nr = ltr * ltr - lti * lti;
    float ni = 2.f * ltr * lti;
    ltr = nr; lti = ni;
  }
  float cr = 0.f, ci = 0.f;
  float2 fin = segfin[(size_t)(b * SEG_) * H_ + c];
  float pmv = prodm[b * SEG_];
  for (int s = 0; s < SEG_; ++s) {
    size_t o = (size_t)(b * SEG_ + s) * H_ + c;
    carries[o] = make_float2(cr, ci);
    float2 finn; float pmn;
    if (s + 1 < SEG_) { finn = segfin[o + H_]; pmn = prodm[b * SEG_ + s + 1]; }
    float nr = fin.x + pmv * (ltr * cr - lti * ci);
    float ni = fin.y + pmv * (ltr * ci + lti * cr);
    cr = nr; ci = ni;
    fin = finn; pmv = pmn;
  }
}

// ---------------------------------------------------------------------------
// Scan pass 3: full scan with injected carry, single h rewrite.
// 8-row chunks, double-buffered loads; stores trail the compute chain.
// ---------------------------------------------------------------------------
__global__ __launch_bounds__(256) void scan_full(
    u16* __restrict__ h, const float* __restrict__ mask,
    const float* __restrict__ params, const float2* __restrict__ carries)
{
  const int s = blockIdx.x, b = blockIdx.y;
  const int c4 = threadIdx.x * 4;
  float lr[4], li[4], sr[4], si[4];
#pragma unroll
  for (int j = 0; j < 4; ++j) {
    int c = c4 + j;
    float nu = expf(params[c]);
    float th = expf(params[H_ + c]);
    float mg = expf(-nu);
    lr[j] = mg * cosf(th);
    li[j] = mg * sinf(th);
    float2 cv = carries[(size_t)(b * SEG_ + s) * H_ + c];
    sr[j] = cv.x; si[j] = cv.y;
  }
  const int t0 = s * T_;
  u16* p = h + (size_t)(b * L_ + t0) * (2 * H_) + c4;
  const float* mp = mask + b * L_ + t0;
  float fac0;
  if (t0 == 0) fac0 = 0.f; else fac0 = mask[b * L_ + t0 - 1];

  ushort4 bre[2][8], bim[2][8];
#pragma unroll
  for (int j = 0; j < 8; ++j) {
    bre[0][j] = *(const ushort4*)(p + (size_t)j * 2 * H_);
    bim[0][j] = *(const ushort4*)(p + (size_t)j * 2 * H_ + H_);
  }
#pragma unroll
  for (int ch = 0; ch < T_ / 8; ++ch) {
    const int cur = ch & 1, nxt = cur ^ 1;
    if (ch < T_ / 8 - 1) {
      const u16* pn = p + (size_t)(ch + 1) * 8 * 2 * H_;
#pragma unroll
      for (int j = 0; j < 8; ++j) {
        bre[nxt][j] = *(const ushort4*)(pn + (size_t)j * 2 * H_);
        bim[nxt][j] = *(const ushort4*)(pn + (size_t)j * 2 * H_ + H_);
      }
    }
#pragma unroll
    for (int j = 0; j < 8; ++j) {
      int i = ch * 8 + j;
      float fac = (i == 0) ? fac0 : mp[i - 1];
      u16 rr[4], ii[4], orr[4], oii[4];
      *(ushort4*)rr = bre[cur][j]; *(ushort4*)ii = bim[cur][j];
#pragma unroll
      for (int k = 0; k < 4; ++k) {
        float ar = fac * sr[k], ai = fac * si[k];
        float nr2 = b2f(rr[k]) + lr[k] * ar - li[k] * ai;
        float ni2 = b2f(ii[k]) + lr[k] * ai + li[k] * ar;
        sr[k] = nr2; si[k] = ni2;
        orr[k] = f2b(nr2); oii[k] = f2b(ni2);
      }
      *(ushort4*)(p + (size_t)i * 2 * H_)      = *(ushort4*)orr;
      *(ushort4*)(p + (size_t)i * 2 * H_ + H_) = *(ushort4*)oii;
    }
  }
}

// ---------------------------------------------------------------------------
// LayerNorm: z = y + x; out = (z-mean)/sqrt(var+eps)*w + b.  One wave per
// 512-wide row (8 elems/lane), 64-lane shuffle reduction, 4 rows per block.
// ---------------------------------------------------------------------------
__global__ __launch_bounds__(256) void ln_kernel(
    const float* __restrict__ y, const float* __restrict__ xg,
    const float* __restrict__ lnw, const float* __restrict__ lnb,
    float* __restrict__ out)
{
  const int wave = threadIdx.x >> 6, lane = threadIdx.x & 63;
  const size_t row = (size_t)blockIdx.x * 4 + wave;
  const float* yr = y + row * 512;
  const float* xr = xg + row * 512;
  float z[8];
  { float4 t = *(const float4*)&yr[lane * 4];        z[0]=t.x; z[1]=t.y; z[2]=t.z; z[3]=t.w; }
  { float4 t = *(const float4*)&yr[256 + lane * 4];  z[4]=t.x; z[5]=t.y; z[6]=t.z; z[7]=t.w; }
  { float4 t = *(const float4*)&xr[lane * 4];        z[0]+=t.x; z[1]+=t.y; z[2]+=t.z; z[3]+=t.w; }
  { float4 t = *(const float4*)&xr[256 + lane * 4];  z[4]+=t.x; z[5]+=t.y; z[6]+=t.z; z[7]+=t.w; }
  float s = 0.f, ss = 0.f;
#pragma unroll
  for (int j = 0; j < 8; ++j) { s += z[j]; ss += z[j] * z[j]; }
#pragma unroll
  for (int o = 32; o > 0; o >>= 1) { s += __shfl_xor(s, o); ss += __shfl_xor(ss, o); }
  const float mean = s * (1.f / 512.f);
  const float var  = ss * (1.f / 512.f) - mean * mean;
  const float inv  = rsqrtf(var + 1e-5f);
  float ov[8];
#pragma unroll
  for (int j = 0; j < 8; ++j) {
    int col = (j < 4) ? (lane * 4 + j) : (256 + lane * 4 + (j - 4));
    ov[j] = (z[j] - mean) * inv * lnw[col] + lnb[col];
  }
  { float4 t; t.x=ov[0]; t.y=ov[1]; t.z=ov[2]; t.w=ov[3];
    *(float4*)&out[row * 512 + lane * 4] = t; }
  { float4 t; t.x=ov[4]; t.y=ov[5]; t.z=ov[6]; t.w=ov[7];
    *(float4*)&out[row * 512 + 256 + lane * 4] = t; }
}

// ---------------------------------------------------------------------------
extern "C" void kernel_launch(void* const* d_in, const int* in_sizes, int n_in,
                              void* d_out, int out_size, void* d_ws, size_t ws_size,
                              hipStream_t stream) {
  (void)in_sizes; (void)n_in; (void)out_size; (void)ws_size;
  const float* x      = (const float*)d_in[0];
  const float* mask   = (const float*)d_in[1];
  const float* params = (const float*)d_in[2];   // [3][1024]: nu_log, theta_log, gamma_log
  const float* Wire   = (const float*)d_in[3];
  const float* Wiim   = (const float*)d_in[4];
  const float* bire   = (const float*)d_in[5];
  const float* biim   = (const float*)d_in[6];
  const float* Wore   = (const float*)d_in[7];
  const float* Woim   = (const float*)d_in[8];
  const float* bore   = (const float*)d_in[9];
  // d_in[10] = b_out_im: only affects Im(y), discarded by .real
  const float* lnw    = (const float*)d_in[11];
  const float* lnb    = (const float*)d_in[12];

  // Workspace (~105 MB). Region [0, 33.5M) time-shared:
  //   xb (gemm1 in) -> segfin[0,4M)+carries[4M,8M)+prodm[8M) -> y (gemm2/ln)
  char* ws = (char*)d_ws;
  u16*    xb      = (u16*)   (ws);                         // 16384*512*2 = 16.7M
  float2* segfin  = (float2*)(ws);                         // 8*64*1024*8 = 4M
  float2* carries = (float2*)(ws + (size_t)4194304);       // 4M
  float*  prodm   = (float*) (ws + (size_t)8388608);       // 2 KB
  float*  y       = (float*) (ws);                         // 16384*512*4 = 33.5M
  u16*    h       = (u16*)   (ws + (size_t)33554432);      // 16384*2048*2 = 67M
  u16*    winb    = (u16*)   (ws + (size_t)100663296);     // 2048*512*2 = 2M
  u16*    wcat    = (u16*)   (ws + (size_t)102760448);     // 512*2048*2 = 2M
  float*  bb      = (float*) (ws + (size_t)104857600);     // 2048*4 = 8 KB

  conv_f32_bf16<<<8192, 256, 0, stream>>>(x, xb, M_ * D_ / 4);
  prep_weights<<<2048, 256, 0, stream>>>(Wire, Wiim, Wore, Woim, bire, biim,
                                         params, winb, wcat, bb);

  // h[re|im] = x @ (gamma*[W_in_re;W_in_im])^T + bb   (M=16384,N=2048,K=512)
  gemm_direct<0><<<dim3(128, 16), 256, 0, stream>>>(
      xb, winb, 512, (void*)h, 2048, bb);

  scan_fin<<<dim3(SEG_, B_), 256, 0, stream>>>(h, mask, params, segfin, prodm);
  scan_carry<<<32, 256, 0, stream>>>(segfin, prodm, params, carries);
  scan_full<<<dim3(SEG_, B_), 256, 0, stream>>>(h, mask, params, carries);

  // y = h_cat @ Wcat^T + b_out_re   (M=16384,N=512,K=2048), fp32 out
  gemm_direct<1><<<dim3(128, 4), 256, 0, stream>>>(
      h, wcat, 2048, (void*)y, 512, bore);

  ln_kernel<<<4096, 256, 0, stream>>>(y, x, lnw, lnb, (float*)d_out);
}

// Round 6
// 258.320 us; speedup vs baseline: 1.5850x; 1.5850x over previous
//
#include <hip/hip_runtime.h>
#include <hip/hip_bf16.h>
#include <cstdint>
#include <cstddef>

// ---------------------------------------------------------------------------
// LRU layer (fp32 I/O): h = scan( (x W_in^T + b_in)*gamma, lambda, mask )
//                       out = LN( Re(h W_out^T + b_out) + x )
// B=8 L=2048 D=512 H=1024. GEMMs: bf16 MFMA fp32-accum, m97-style LDS-DMA
// staging (round-5 direct-load experiment was 2.4x WORSE - keep DMA), BK=64
// (2 K=32 sub-steps per barrier) to halve the per-iteration drain/barrier
// cost that dominates at ~1090cy/iter. Operand-swapped MFMA epilogue
// (4-consecutive-n packed stores), gamma folded into weights at prep.
// ---------------------------------------------------------------------------

typedef unsigned short u16;
typedef __attribute__((ext_vector_type(8))) short bf16x8;   // 8 bf16 = 4 VGPRs
typedef __attribute__((ext_vector_type(4))) float f32x4;

#define B_    8
#define L_    2048
#define D_    512
#define H_    1024
#define M_    (B_ * L_)      // 16384 rows
#define SEG_  64             // scan segments (512 blocks)
#define T_    (L_ / SEG_)    // 32 steps/segment

__device__ __forceinline__ float b2f(u16 u) {
  union { unsigned int i; float f; } v; v.i = ((unsigned int)u) << 16; return v.f;
}
__device__ __forceinline__ u16 f2b(float f) {
  union { float f; unsigned int i; } v; v.f = f;
  unsigned int x = v.i;
  return (u16)((x + 0x7fffu + ((x >> 16) & 1u)) >> 16);   // RNE
}

// async global->LDS, 16B per lane. LDS dst must be uniform-base + lane*16.
__device__ __forceinline__ void gl2lds16(const void* g, void* l) {
  __builtin_amdgcn_global_load_lds(
      (const __attribute__((address_space(1))) void*)g,
      (__attribute__((address_space(3))) void*)l, 16, 0, 0);
}

// XOR swizzle of the 8 16B-chunks in a 64-wide K row (BK=64): spreads
// ds_read_b128 bank-start groups across all 8 4-bank groups.
__device__ __forceinline__ int ksw8(int row, int c) {
  return (c ^ (row & 7)) & 7;
}

// ---------------------------------------------------------------------------
// fp32 -> bf16 elementwise, 4 elems/thread (n4 = n/4 float4 groups)
// ---------------------------------------------------------------------------
__global__ __launch_bounds__(256) void conv_f32_bf16(
    const float* __restrict__ in, u16* __restrict__ out, int n4)
{
  int i = blockIdx.x * 256 + threadIdx.x;
  if (i < n4) {
    float4 v = ((const float4*)in)[i];
    ushort4 o;
    o.x = f2b(v.x); o.y = f2b(v.y); o.z = f2b(v.z); o.w = f2b(v.w);
    ((ushort4*)out)[i] = o;
  }
}

// Weight prep: winb rows pre-scaled by gamma:
//   winb[n][k] = bf16(W_in[n][k] * gamma[n&1023]),  rows [re(1024) | im(1024)]
//   wcat[d][c]=W_out_re[d][c], wcat[d][1024+c]=-W_out_im[d][c]
//   bb[n] = b_in[n] * gamma[n&1023]   (fp32, 2048)
__global__ __launch_bounds__(256) void prep_weights(
    const float* __restrict__ wire, const float* __restrict__ wiim,
    const float* __restrict__ wore, const float* __restrict__ woim,
    const float* __restrict__ bire, const float* __restrict__ biim,
    const float* __restrict__ params,
    u16* __restrict__ winb, u16* __restrict__ wcat, float* __restrict__ bb)
{
  int i = blockIdx.x * 256 + threadIdx.x;        // 0 .. 524287
  float g = expf(params[2 * H_ + (i >> 9)]);     // gamma for W_in row i>>9
  winb[i]           = f2b(wire[i] * g);
  winb[H_ * D_ + i] = f2b(wiim[i] * g);
  int d = i >> 10, c = i & 1023;
  wcat[(size_t)d * 2048 + c]        = f2b(wore[i]);
  wcat[(size_t)d * 2048 + 1024 + c] = f2b(-woim[i]);
  if (i < 2048) {
    float gb = expf(params[2 * H_ + (i & (H_ - 1))]);
    bb[i] = ((i < 1024) ? bire[i] : biim[i - 1024]) * gb;
  }
}

// ---------------------------------------------------------------------------
// gemm_bt: C(M x N) = A(M x K) * B(N x K)^T.  128x128 tile, 4 waves 2x2
// (64x64 each, 4x4 of 16x16x32 MFMA), BK=64: one barrier pair covers two
// K=32 MFMA sub-steps (halves drain/barrier events vs BK=32).
// LDS 2 x 16KB, global_load_lds 16B staging (4 chunks/thread per matrix).
// Operand-swapped MFMA: D row (q*4+i) = n, col (r) = m -> 4-consecutive-n
// packed stores.  Grid: blockIdx.x = m-block (fast) -> A-sharers on one XCD.
// MODE 0: out bf16, val = acc + p0[n];  MODE 1: out fp32, val = acc + p0[n].
// ---------------------------------------------------------------------------
template <int MODE>
__global__ __launch_bounds__(256, 3) void gemm_bt(
    const u16* __restrict__ A, const u16* __restrict__ Bp, int K,
    void* __restrict__ outp, int ldc, const float* __restrict__ p0)
{
  __shared__ __align__(16) u16 sA[128 * 64];   // 16 KB
  __shared__ __align__(16) u16 sB[128 * 64];   // 16 KB

  const int tid  = threadIdx.x;
  const int lane = tid & 63;
  const int wave = tid >> 6;
  const int wm = wave >> 1, wn = wave & 1;           // 2x2 wave grid
  const int m0 = blockIdx.x * 128;                   // m on fast axis
  const int n0 = blockIdx.y * 128;

  f32x4 acc[4][4];
#pragma unroll
  for (int i = 0; i < 4; ++i)
#pragma unroll
    for (int j = 0; j < 4; ++j) { f32x4 z = {0.f, 0.f, 0.f, 0.f}; acc[i][j] = z; }

  const int q = lane >> 4;       // quad 0..3 -> k-offset q*8 within sub-step
  const int r = lane & 15;       // row index within 16

  for (int k0 = 0; k0 < K; k0 += 64) {
    // stage A,B 128x64 tiles: 1024 chunks of 16B each, 4 per thread/matrix
#pragma unroll
    for (int it = 0; it < 4; ++it) {
      int ci  = it * 256 + tid;          // LDS slot; dst = uniform + lane*16
      int row = ci >> 3;
      int kc  = ksw8(row, ci & 7);       // swizzled source chunk
      gl2lds16(A  + (size_t)(m0 + row) * K + k0 + kc * 8, &sA[ci * 8]);
      gl2lds16(Bp + (size_t)(n0 + row) * K + k0 + kc * 8, &sB[ci * 8]);
    }
    __syncthreads();

#pragma unroll
    for (int kk = 0; kk < 2; ++kk) {     // two K=32 sub-steps per barrier
      const int cs = kk * 4 + q;         // source chunk for this frag
      bf16x8 af[4], bfv[4];
#pragma unroll
      for (int mt = 0; mt < 4; ++mt) {
        int arow = wm * 64 + mt * 16 + r;
        int slot = arow * 8 + ksw8(arow, cs);
        af[mt] = *(const bf16x8*)&sA[slot * 8];
      }
#pragma unroll
      for (int nt = 0; nt < 4; ++nt) {
        int brow = wn * 64 + nt * 16 + r;
        int slot = brow * 8 + ksw8(brow, cs);
        bfv[nt] = *(const bf16x8*)&sB[slot * 8];
      }
#pragma unroll
      for (int mt = 0; mt < 4; ++mt)
#pragma unroll
        for (int nt = 0; nt < 4; ++nt)
          acc[mt][nt] = __builtin_amdgcn_mfma_f32_16x16x32_bf16(
              bfv[nt], af[mt], acc[mt][nt], 0, 0, 0);
    }
    __syncthreads();
  }

  // epilogue: thread holds n = nb4..nb4+3 (contiguous) for each of 16 tiles
#pragma unroll
  for (int nt = 0; nt < 4; ++nt) {
    const int nb4 = n0 + wn * 64 + nt * 16 + q * 4;
    const float4 b4 = *(const float4*)&p0[nb4];
#pragma unroll
    for (int mt = 0; mt < 4; ++mt) {
      const int mg = m0 + wm * 64 + mt * 16 + r;
      if (MODE == 0) {
        ushort4 o;
        o.x = f2b(acc[mt][nt][0] + b4.x);
        o.y = f2b(acc[mt][nt][1] + b4.y);
        o.z = f2b(acc[mt][nt][2] + b4.z);
        o.w = f2b(acc[mt][nt][3] + b4.w);
        *(ushort4*)&((u16*)outp)[(size_t)mg * ldc + nb4] = o;
      } else {
        float4 o;
        o.x = acc[mt][nt][0] + b4.x;
        o.y = acc[mt][nt][1] + b4.y;
        o.z = acc[mt][nt][2] + b4.z;
        o.w = acc[mt][nt][3] + b4.w;
        *(float4*)&((float*)outp)[(size_t)mg * ldc + nb4] = o;
      }
    }
  }
}

// ---------------------------------------------------------------------------
// Scan pass 1 (read-only): segment-final state (zero init) + mask product.
// 8-row chunks, double-buffered loads.  h_t = x_t + lambda*m[t-1]*h_{t-1}.
// ---------------------------------------------------------------------------
__global__ __launch_bounds__(256) void scan_fin(
    const u16* __restrict__ h, const float* __restrict__ mask,
    const float* __restrict__ params, float2* __restrict__ segfin,
    float* __restrict__ prodm)
{
  const int s = blockIdx.x, b = blockIdx.y;
  const int c4 = threadIdx.x * 4;
  float lr[4], li[4];
#pragma unroll
  for (int j = 0; j < 4; ++j) {
    int c = c4 + j;
    float nu = expf(params[c]);
    float th = expf(params[H_ + c]);
    float mg = expf(-nu);
    lr[j] = mg * cosf(th);
    li[j] = mg * sinf(th);
  }
  const int t0 = s * T_;
  const u16* p = h + (size_t)(b * L_ + t0) * (2 * H_) + c4;
  const float* mp = mask + b * L_ + t0;
  float fac0;                 // block-uniform: no OOB speculative load
  if (t0 == 0) fac0 = 0.f; else fac0 = mask[b * L_ + t0 - 1];

  ushort4 bre[2][8], bim[2][8];
#pragma unroll
  for (int j = 0; j < 8; ++j) {
    bre[0][j] = *(const ushort4*)(p + (size_t)j * 2 * H_);
    bim[0][j] = *(const ushort4*)(p + (size_t)j * 2 * H_ + H_);
  }
  float sr[4] = {0, 0, 0, 0}, si[4] = {0, 0, 0, 0};
  float pm = 1.f;
#pragma unroll
  for (int ch = 0; ch < T_ / 8; ++ch) {
    const int cur = ch & 1, nxt = cur ^ 1;
    if (ch < T_ / 8 - 1) {
      const u16* pn = p + (size_t)(ch + 1) * 8 * 2 * H_;
#pragma unroll
      for (int j = 0; j < 8; ++j) {
        bre[nxt][j] = *(const ushort4*)(pn + (size_t)j * 2 * H_);
        bim[nxt][j] = *(const ushort4*)(pn + (size_t)j * 2 * H_ + H_);
      }
    }
#pragma unroll
    for (int j = 0; j < 8; ++j) {
      int i = ch * 8 + j;
      float fac = (i == 0) ? fac0 : mp[i - 1];
      pm *= fac;
      u16 rr[4], ii[4];
      *(ushort4*)rr = bre[cur][j]; *(ushort4*)ii = bim[cur][j];
#pragma unroll
      for (int k = 0; k < 4; ++k) {
        float ar = fac * sr[k], ai = fac * si[k];
        sr[k] = b2f(rr[k]) + lr[k] * ar - li[k] * ai;
        si[k] = b2f(ii[k]) + lr[k] * ai + li[k] * ar;
      }
    }
  }
#pragma unroll
  for (int j = 0; j < 4; ++j)
    segfin[(size_t)(b * SEG_ + s) * H_ + c4 + j] = make_float2(sr[j], si[j]);
  if (threadIdx.x == 0) prodm[b * SEG_ + s] = pm;
}

// ---------------------------------------------------------------------------
// Scan pass 2: carries[s] = state entering segment s.
// carry_{s+1} = fin_s + prodm_s * lambda^T * carry_s; lambda^T via 5
// squarings (T=32).  Next-iter loads prefetched past the dependent update.
// ---------------------------------------------------------------------------
__global__ __launch_bounds__(256) void scan_carry(
    const float2* __restrict__ segfin, const float* __restrict__ prodm,
    const float* __restrict__ params, float2* __restrict__ carries)
{
  int idx = blockIdx.x * 256 + threadIdx.x;   // 0..8191
  int b = idx >> 10, c = idx & 1023;
  float nu = expf(params[c]);
  float th = expf(params[H_ + c]);
  float mg = expf(-nu);
  float ltr = mg * cosf(th), lti = mg * sinf(th);
#pragma unroll
  for (int sq = 0; sq < 5; ++sq) {            // lambda^(2^5) = lambda^T, T=32
    float nr = ltr * ltr - lti * lti;
    float ni = 2.f * ltr * lti;
    ltr = nr; lti = ni;
  }
  float cr = 0.f, ci = 0.f;
  float2 fin = segfin[(size_t)(b * SEG_) * H_ + c];
  float pmv = prodm[b * SEG_];
  for (int s = 0; s < SEG_; ++s) {
    size_t o = (size_t)(b * SEG_ + s) * H_ + c;
    carries[o] = make_float2(cr, ci);
    float2 finn; float pmn;
    if (s + 1 < SEG_) { finn = segfin[o + H_]; pmn = prodm[b * SEG_ + s + 1]; }
    float nr = fin.x + pmv * (ltr * cr - lti * ci);
    float ni = fin.y + pmv * (ltr * ci + lti * cr);
    cr = nr; ci = ni;
    fin = finn; pmv = pmn;
  }
}

// ---------------------------------------------------------------------------
// Scan pass 3: full scan with injected carry, single h rewrite.
// 8-row chunks, double-buffered loads; stores trail the compute chain.
// ---------------------------------------------------------------------------
__global__ __launch_bounds__(256) void scan_full(
    u16* __restrict__ h, const float* __restrict__ mask,
    const float* __restrict__ params, const float2* __restrict__ carries)
{
  const int s = blockIdx.x, b = blockIdx.y;
  const int c4 = threadIdx.x * 4;
  float lr[4], li[4], sr[4], si[4];
#pragma unroll
  for (int j = 0; j < 4; ++j) {
    int c = c4 + j;
    float nu = expf(params[c]);
    float th = expf(params[H_ + c]);
    float mg = expf(-nu);
    lr[j] = mg * cosf(th);
    li[j] = mg * sinf(th);
    float2 cv = carries[(size_t)(b * SEG_ + s) * H_ + c];
    sr[j] = cv.x; si[j] = cv.y;
  }
  const int t0 = s * T_;
  u16* p = h + (size_t)(b * L_ + t0) * (2 * H_) + c4;
  const float* mp = mask + b * L_ + t0;
  float fac0;
  if (t0 == 0) fac0 = 0.f; else fac0 = mask[b * L_ + t0 - 1];

  ushort4 bre[2][8], bim[2][8];
#pragma unroll
  for (int j = 0; j < 8; ++j) {
    bre[0][j] = *(const ushort4*)(p + (size_t)j * 2 * H_);
    bim[0][j] = *(const ushort4*)(p + (size_t)j * 2 * H_ + H_);
  }
#pragma unroll
  for (int ch = 0; ch < T_ / 8; ++ch) {
    const int cur = ch & 1, nxt = cur ^ 1;
    if (ch < T_ / 8 - 1) {
      const u16* pn = p + (size_t)(ch + 1) * 8 * 2 * H_;
#pragma unroll
      for (int j = 0; j < 8; ++j) {
        bre[nxt][j] = *(const ushort4*)(pn + (size_t)j * 2 * H_);
        bim[nxt][j] = *(const ushort4*)(pn + (size_t)j * 2 * H_ + H_);
      }
    }
#pragma unroll
    for (int j = 0; j < 8; ++j) {
      int i = ch * 8 + j;
      float fac = (i == 0) ? fac0 : mp[i - 1];
      u16 rr[4], ii[4], orr[4], oii[4];
      *(ushort4*)rr = bre[cur][j]; *(ushort4*)ii = bim[cur][j];
#pragma unroll
      for (int k = 0; k < 4; ++k) {
        float ar = fac * sr[k], ai = fac * si[k];
        float nr2 = b2f(rr[k]) + lr[k] * ar - li[k] * ai;
        float ni2 = b2f(ii[k]) + lr[k] * ai + li[k] * ar;
        sr[k] = nr2; si[k] = ni2;
        orr[k] = f2b(nr2); oii[k] = f2b(ni2);
      }
      *(ushort4*)(p + (size_t)i * 2 * H_)      = *(ushort4*)orr;
      *(ushort4*)(p + (size_t)i * 2 * H_ + H_) = *(ushort4*)oii;
    }
  }
}

// ---------------------------------------------------------------------------
// LayerNorm: z = y + x; out = (z-mean)/sqrt(var+eps)*w + b.  One wave per
// 512-wide row (8 elems/lane), 64-lane shuffle reduction, 4 rows per block.
// ---------------------------------------------------------------------------
__global__ __launch_bounds__(256) void ln_kernel(
    const float* __restrict__ y, const float* __restrict__ xg,
    const float* __restrict__ lnw, const float* __restrict__ lnb,
    float* __restrict__ out)
{
  const int wave = threadIdx.x >> 6, lane = threadIdx.x & 63;
  const size_t row = (size_t)blockIdx.x * 4 + wave;
  const float* yr = y + row * 512;
  const float* xr = xg + row * 512;
  float z[8];
  { float4 t = *(const float4*)&yr[lane * 4];        z[0]=t.x; z[1]=t.y; z[2]=t.z; z[3]=t.w; }
  { float4 t = *(const float4*)&yr[256 + lane * 4];  z[4]=t.x; z[5]=t.y; z[6]=t.z; z[7]=t.w; }
  { float4 t = *(const float4*)&xr[lane * 4];        z[0]+=t.x; z[1]+=t.y; z[2]+=t.z; z[3]+=t.w; }
  { float4 t = *(const float4*)&xr[256 + lane * 4];  z[4]+=t.x; z[5]+=t.y; z[6]+=t.z; z[7]+=t.w; }
  float s = 0.f, ss = 0.f;
#pragma unroll
  for (int j = 0; j < 8; ++j) { s += z[j]; ss += z[j] * z[j]; }
#pragma unroll
  for (int o = 32; o > 0; o >>= 1) { s += __shfl_xor(s, o); ss += __shfl_xor(ss, o); }
  const float mean = s * (1.f / 512.f);
  const float var  = ss * (1.f / 512.f) - mean * mean;
  const float inv  = rsqrtf(var + 1e-5f);
  float ov[8];
#pragma unroll
  for (int j = 0; j < 8; ++j) {
    int col = (j < 4) ? (lane * 4 + j) : (256 + lane * 4 + (j - 4));
    ov[j] = (z[j] - mean) * inv * lnw[col] + lnb[col];
  }
  { float4 t; t.x=ov[0]; t.y=ov[1]; t.z=ov[2]; t.w=ov[3];
    *(float4*)&out[row * 512 + lane * 4] = t; }
  { float4 t; t.x=ov[4]; t.y=ov[5]; t.z=ov[6]; t.w=ov[7];
    *(float4*)&out[row * 512 + 256 + lane * 4] = t; }
}

// ---------------------------------------------------------------------------
extern "C" void kernel_launch(void* const* d_in, const int* in_sizes, int n_in,
                              void* d_out, int out_size, void* d_ws, size_t ws_size,
                              hipStream_t stream) {
  (void)in_sizes; (void)n_in; (void)out_size; (void)ws_size;
  const float* x      = (const float*)d_in[0];
  const float* mask   = (const float*)d_in[1];
  const float* params = (const float*)d_in[2];   // [3][1024]: nu_log, theta_log, gamma_log
  const float* Wire   = (const float*)d_in[3];
  const float* Wiim   = (const float*)d_in[4];
  const float* bire   = (const float*)d_in[5];
  const float* biim   = (const float*)d_in[6];
  const float* Wore   = (const float*)d_in[7];
  const float* Woim   = (const float*)d_in[8];
  const float* bore   = (const float*)d_in[9];
  // d_in[10] = b_out_im: only affects Im(y), discarded by .real
  const float* lnw    = (const float*)d_in[11];
  const float* lnb    = (const float*)d_in[12];

  // Workspace (~105 MB). Region [0, 33.5M) time-shared:
  //   xb (gemm1 in) -> segfin[0,4M)+carries[4M,8M)+prodm[8M) -> y (gemm2/ln)
  char* ws = (char*)d_ws;
  u16*    xb      = (u16*)   (ws);                         // 16384*512*2 = 16.7M
  float2* segfin  = (float2*)(ws);                         // 8*64*1024*8 = 4M
  float2* carries = (float2*)(ws + (size_t)4194304);       // 4M
  float*  prodm   = (float*) (ws + (size_t)8388608);       // 2 KB
  float*  y       = (float*) (ws);                         // 16384*512*4 = 33.5M
  u16*    h       = (u16*)   (ws + (size_t)33554432);      // 16384*2048*2 = 67M
  u16*    winb    = (u16*)   (ws + (size_t)100663296);     // 2048*512*2 = 2M
  u16*    wcat    = (u16*)   (ws + (size_t)102760448);     // 512*2048*2 = 2M
  float*  bb      = (float*) (ws + (size_t)104857600);     // 2048*4 = 8 KB

  conv_f32_bf16<<<8192, 256, 0, stream>>>(x, xb, M_ * D_ / 4);
  prep_weights<<<2048, 256, 0, stream>>>(Wire, Wiim, Wore, Woim, bire, biim,
                                         params, winb, wcat, bb);

  // h[re|im] = x @ (gamma*[W_in_re;W_in_im])^T + bb   (M=16384,N=2048,K=512)
  gemm_bt<0><<<dim3(128, 16), 256, 0, stream>>>(
      xb, winb, 512, (void*)h, 2048, bb);

  scan_fin<<<dim3(SEG_, B_), 256, 0, stream>>>(h, mask, params, segfin, prodm);
  scan_carry<<<32, 256, 0, stream>>>(segfin, prodm, params, carries);
  scan_full<<<dim3(SEG_, B_), 256, 0, stream>>>(h, mask, params, carries);

  // y = h_cat @ Wcat^T + b_out_re   (M=16384,N=512,K=2048), fp32 out
  gemm_bt<1><<<dim3(128, 4), 256, 0, stream>>>(
      h, wcat, 2048, (void*)y, 512, bore);

  ln_kernel<<<4096, 256, 0, stream>>>(y, x, lnw, lnb, (float*)d_out);
}

// Round 7
// 254.607 us; speedup vs baseline: 1.6081x; 1.0146x over previous
//
#include <hip/hip_runtime.h>
#include <hip/hip_bf16.h>
#include <cstdint>
#include <cstddef>

// ---------------------------------------------------------------------------
// LRU layer (fp32 I/O): h = scan( (x W_in^T + b_in)*gamma, lambda, mask )
//                       out = LN( Re(h W_out^T + b_out) + x )
// B=8 L=2048 D=512 H=1024.  Model from rounds 2-6: gemm time ~ staged bytes
// (LDS-DMA ~9.4 TB/s aggregate).  gemm1 switches to BM=256 x BN=128 tile:
// staged 537 -> 403 MB (-25%).  gemm2 stays 128x128 (needs >=512 blocks for
// 2/CU residency).  BK=64, operand-swapped MFMA epilogue, gamma pre-folded.
// ---------------------------------------------------------------------------

typedef unsigned short u16;
typedef __attribute__((ext_vector_type(8))) short bf16x8;   // 8 bf16 = 4 VGPRs
typedef __attribute__((ext_vector_type(4))) float f32x4;

#define B_    8
#define L_    2048
#define D_    512
#define H_    1024
#define M_    (B_ * L_)      // 16384 rows
#define SEG_  64             // scan segments (512 blocks)
#define T_    (L_ / SEG_)    // 32 steps/segment

__device__ __forceinline__ float b2f(u16 u) {
  union { unsigned int i; float f; } v; v.i = ((unsigned int)u) << 16; return v.f;
}
__device__ __forceinline__ u16 f2b(float f) {
  union { float f; unsigned int i; } v; v.f = f;
  unsigned int x = v.i;
  return (u16)((x + 0x7fffu + ((x >> 16) & 1u)) >> 16);   // RNE
}

// async global->LDS, 16B per lane. LDS dst must be uniform-base + lane*16.
__device__ __forceinline__ void gl2lds16(const void* g, void* l) {
  __builtin_amdgcn_global_load_lds(
      (const __attribute__((address_space(1))) void*)g,
      (__attribute__((address_space(3))) void*)l, 16, 0, 0);
}

// XOR swizzle of the 8 16B-chunks in a 64-wide K row (BK=64).
__device__ __forceinline__ int ksw8(int row, int c) {
  return (c ^ (row & 7)) & 7;
}

// ---------------------------------------------------------------------------
// fp32 -> bf16 elementwise, 4 elems/thread (n4 = n/4 float4 groups)
// ---------------------------------------------------------------------------
__global__ __launch_bounds__(256) void conv_f32_bf16(
    const float* __restrict__ in, u16* __restrict__ out, int n4)
{
  int i = blockIdx.x * 256 + threadIdx.x;
  if (i < n4) {
    float4 v = ((const float4*)in)[i];
    ushort4 o;
    o.x = f2b(v.x); o.y = f2b(v.y); o.z = f2b(v.z); o.w = f2b(v.w);
    ((ushort4*)out)[i] = o;
  }
}

// Weight prep: winb rows pre-scaled by gamma:
//   winb[n][k] = bf16(W_in[n][k] * gamma[n&1023]),  rows [re(1024) | im(1024)]
//   wcat[d][c]=W_out_re[d][c], wcat[d][1024+c]=-W_out_im[d][c]
//   bb[n] = b_in[n] * gamma[n&1023]   (fp32, 2048)
__global__ __launch_bounds__(256) void prep_weights(
    const float* __restrict__ wire, const float* __restrict__ wiim,
    const float* __restrict__ wore, const float* __restrict__ woim,
    const float* __restrict__ bire, const float* __restrict__ biim,
    const float* __restrict__ params,
    u16* __restrict__ winb, u16* __restrict__ wcat, float* __restrict__ bb)
{
  int i = blockIdx.x * 256 + threadIdx.x;        // 0 .. 524287
  float g = expf(params[2 * H_ + (i >> 9)]);     // gamma for W_in row i>>9
  winb[i]           = f2b(wire[i] * g);
  winb[H_ * D_ + i] = f2b(wiim[i] * g);
  int d = i >> 10, c = i & 1023;
  wcat[(size_t)d * 2048 + c]        = f2b(wore[i]);
  wcat[(size_t)d * 2048 + 1024 + c] = f2b(-woim[i]);
  if (i < 2048) {
    float gb = expf(params[2 * H_ + (i & (H_ - 1))]);
    bb[i] = ((i < 1024) ? bire[i] : biim[i - 1024]) * gb;
  }
}

// ---------------------------------------------------------------------------
// gemm1_256: C(M x N) = A(M x K) * B(N x K)^T, BM=256 BN=128 BK=64.
// 4 waves in 2x2; wave tile 128x64 = 8x4 of 16x16x32 MFMA.  Staged bytes
// per block = 384*K*2 (25% less per output than 128x128).  LDS 48 KB,
// acc 32 x f32x4, ~200 VGPR -> 2 blocks/CU.
// Operand-swapped MFMA: D row (q*4+i) = n, col (r) = m.
// out bf16, val = acc + p0[n].
// ---------------------------------------------------------------------------
__global__ __launch_bounds__(256, 2) void gemm1_256(
    const u16* __restrict__ A, const u16* __restrict__ Bp, int K,
    u16* __restrict__ outp, int ldc, const float* __restrict__ p0)
{
  __shared__ __align__(16) u16 sA[256 * 64];   // 32 KB
  __shared__ __align__(16) u16 sB[128 * 64];   // 16 KB

  const int tid  = threadIdx.x;
  const int lane = tid & 63;
  const int wave = tid >> 6;
  const int wm = wave >> 1, wn = wave & 1;     // wave tile: 128 rows x 64 cols
  const int m0 = blockIdx.x * 256;             // m on fast axis (XCD share)
  const int n0 = blockIdx.y * 128;

  f32x4 acc[8][4];
#pragma unroll
  for (int i = 0; i < 8; ++i)
#pragma unroll
    for (int j = 0; j < 4; ++j) { f32x4 z = {0.f, 0.f, 0.f, 0.f}; acc[i][j] = z; }

  const int q = lane >> 4;       // quad 0..3 -> k-offset q*8 within sub-step
  const int r = lane & 15;       // row index within 16

  for (int k0 = 0; k0 < K; k0 += 64) {
    // stage A 256x64 (2048 chunks) + B 128x64 (1024 chunks), 16B each
#pragma unroll
    for (int it = 0; it < 8; ++it) {
      int ci  = it * 256 + tid;
      int row = ci >> 3;
      int kc  = ksw8(row, ci & 7);
      gl2lds16(A + (size_t)(m0 + row) * K + k0 + kc * 8, &sA[ci * 8]);
    }
#pragma unroll
    for (int it = 0; it < 4; ++it) {
      int ci  = it * 256 + tid;
      int row = ci >> 3;
      int kc  = ksw8(row, ci & 7);
      gl2lds16(Bp + (size_t)(n0 + row) * K + k0 + kc * 8, &sB[ci * 8]);
    }
    __syncthreads();

#pragma unroll
    for (int kk = 0; kk < 2; ++kk) {     // two K=32 sub-steps per barrier
      const int cs = kk * 4 + q;
      bf16x8 af[8], bfv[4];
#pragma unroll
      for (int mt = 0; mt < 8; ++mt) {
        int arow = wm * 128 + mt * 16 + r;
        int slot = arow * 8 + ksw8(arow, cs);
        af[mt] = *(const bf16x8*)&sA[slot * 8];
      }
#pragma unroll
      for (int nt = 0; nt < 4; ++nt) {
        int brow = wn * 64 + nt * 16 + r;
        int slot = brow * 8 + ksw8(brow, cs);
        bfv[nt] = *(const bf16x8*)&sB[slot * 8];
      }
#pragma unroll
      for (int mt = 0; mt < 8; ++mt)
#pragma unroll
        for (int nt = 0; nt < 4; ++nt)
          acc[mt][nt] = __builtin_amdgcn_mfma_f32_16x16x32_bf16(
              bfv[nt], af[mt], acc[mt][nt], 0, 0, 0);
    }
    __syncthreads();
  }

#pragma unroll
  for (int nt = 0; nt < 4; ++nt) {
    const int nb4 = n0 + wn * 64 + nt * 16 + q * 4;
    const float4 b4 = *(const float4*)&p0[nb4];
#pragma unroll
    for (int mt = 0; mt < 8; ++mt) {
      const int mg = m0 + wm * 128 + mt * 16 + r;
      ushort4 o;
      o.x = f2b(acc[mt][nt][0] + b4.x);
      o.y = f2b(acc[mt][nt][1] + b4.y);
      o.z = f2b(acc[mt][nt][2] + b4.z);
      o.w = f2b(acc[mt][nt][3] + b4.w);
      *(ushort4*)&outp[(size_t)mg * ldc + nb4] = o;
    }
  }
}

// ---------------------------------------------------------------------------
// gemm_bt: 128x128 tile, BK=64 (round-6 best known) for gemm2.
// MODE 1: out fp32, val = acc + p0[n].
// ---------------------------------------------------------------------------
__global__ __launch_bounds__(256, 3) void gemm_bt(
    const u16* __restrict__ A, const u16* __restrict__ Bp, int K,
    float* __restrict__ outp, int ldc, const float* __restrict__ p0)
{
  __shared__ __align__(16) u16 sA[128 * 64];   // 16 KB
  __shared__ __align__(16) u16 sB[128 * 64];   // 16 KB

  const int tid  = threadIdx.x;
  const int lane = tid & 63;
  const int wave = tid >> 6;
  const int wm = wave >> 1, wn = wave & 1;
  const int m0 = blockIdx.x * 128;
  const int n0 = blockIdx.y * 128;

  f32x4 acc[4][4];
#pragma unroll
  for (int i = 0; i < 4; ++i)
#pragma unroll
    for (int j = 0; j < 4; ++j) { f32x4 z = {0.f, 0.f, 0.f, 0.f}; acc[i][j] = z; }

  const int q = lane >> 4;
  const int r = lane & 15;

  for (int k0 = 0; k0 < K; k0 += 64) {
#pragma unroll
    for (int it = 0; it < 4; ++it) {
      int ci  = it * 256 + tid;
      int row = ci >> 3;
      int kc  = ksw8(row, ci & 7);
      gl2lds16(A  + (size_t)(m0 + row) * K + k0 + kc * 8, &sA[ci * 8]);
      gl2lds16(Bp + (size_t)(n0 + row) * K + k0 + kc * 8, &sB[ci * 8]);
    }
    __syncthreads();

#pragma unroll
    for (int kk = 0; kk < 2; ++kk) {
      const int cs = kk * 4 + q;
      bf16x8 af[4], bfv[4];
#pragma unroll
      for (int mt = 0; mt < 4; ++mt) {
        int arow = wm * 64 + mt * 16 + r;
        int slot = arow * 8 + ksw8(arow, cs);
        af[mt] = *(const bf16x8*)&sA[slot * 8];
      }
#pragma unroll
      for (int nt = 0; nt < 4; ++nt) {
        int brow = wn * 64 + nt * 16 + r;
        int slot = brow * 8 + ksw8(brow, cs);
        bfv[nt] = *(const bf16x8*)&sB[slot * 8];
      }
#pragma unroll
      for (int mt = 0; mt < 4; ++mt)
#pragma unroll
        for (int nt = 0; nt < 4; ++nt)
          acc[mt][nt] = __builtin_amdgcn_mfma_f32_16x16x32_bf16(
              bfv[nt], af[mt], acc[mt][nt], 0, 0, 0);
    }
    __syncthreads();
  }

#pragma unroll
  for (int nt = 0; nt < 4; ++nt) {
    const int nb4 = n0 + wn * 64 + nt * 16 + q * 4;
    const float4 b4 = *(const float4*)&p0[nb4];
#pragma unroll
    for (int mt = 0; mt < 4; ++mt) {
      const int mg = m0 + wm * 64 + mt * 16 + r;
      float4 o;
      o.x = acc[mt][nt][0] + b4.x;
      o.y = acc[mt][nt][1] + b4.y;
      o.z = acc[mt][nt][2] + b4.z;
      o.w = acc[mt][nt][3] + b4.w;
      *(float4*)&outp[(size_t)mg * ldc + nb4] = o;
    }
  }
}

// ---------------------------------------------------------------------------
// Scan pass 1 (read-only): segment-final state (zero init) + mask product.
// ---------------------------------------------------------------------------
__global__ __launch_bounds__(256) void scan_fin(
    const u16* __restrict__ h, const float* __restrict__ mask,
    const float* __restrict__ params, float2* __restrict__ segfin,
    float* __restrict__ prodm)
{
  const int s = blockIdx.x, b = blockIdx.y;
  const int c4 = threadIdx.x * 4;
  float lr[4], li[4];
#pragma unroll
  for (int j = 0; j < 4; ++j) {
    int c = c4 + j;
    float nu = expf(params[c]);
    float th = expf(params[H_ + c]);
    float mg = expf(-nu);
    lr[j] = mg * cosf(th);
    li[j] = mg * sinf(th);
  }
  const int t0 = s * T_;
  const u16* p = h + (size_t)(b * L_ + t0) * (2 * H_) + c4;
  const float* mp = mask + b * L_ + t0;
  float fac0;
  if (t0 == 0) fac0 = 0.f; else fac0 = mask[b * L_ + t0 - 1];

  ushort4 bre[2][8], bim[2][8];
#pragma unroll
  for (int j = 0; j < 8; ++j) {
    bre[0][j] = *(const ushort4*)(p + (size_t)j * 2 * H_);
    bim[0][j] = *(const ushort4*)(p + (size_t)j * 2 * H_ + H_);
  }
  float sr[4] = {0, 0, 0, 0}, si[4] = {0, 0, 0, 0};
  float pm = 1.f;
#pragma unroll
  for (int ch = 0; ch < T_ / 8; ++ch) {
    const int cur = ch & 1, nxt = cur ^ 1;
    if (ch < T_ / 8 - 1) {
      const u16* pn = p + (size_t)(ch + 1) * 8 * 2 * H_;
#pragma unroll
      for (int j = 0; j < 8; ++j) {
        bre[nxt][j] = *(const ushort4*)(pn + (size_t)j * 2 * H_);
        bim[nxt][j] = *(const ushort4*)(pn + (size_t)j * 2 * H_ + H_);
      }
    }
#pragma unroll
    for (int j = 0; j < 8; ++j) {
      int i = ch * 8 + j;
      float fac = (i == 0) ? fac0 : mp[i - 1];
      pm *= fac;
      u16 rr[4], ii[4];
      *(ushort4*)rr = bre[cur][j]; *(ushort4*)ii = bim[cur][j];
#pragma unroll
      for (int k = 0; k < 4; ++k) {
        float ar = fac * sr[k], ai = fac * si[k];
        sr[k] = b2f(rr[k]) + lr[k] * ar - li[k] * ai;
        si[k] = b2f(ii[k]) + lr[k] * ai + li[k] * ar;
      }
    }
  }
#pragma unroll
  for (int j = 0; j < 4; ++j)
    segfin[(size_t)(b * SEG_ + s) * H_ + c4 + j] = make_float2(sr[j], si[j]);
  if (threadIdx.x == 0) prodm[b * SEG_ + s] = pm;
}

// ---------------------------------------------------------------------------
// Scan pass 2: carries[s] = state entering segment s.
// ---------------------------------------------------------------------------
__global__ __launch_bounds__(256) void scan_carry(
    const float2* __restrict__ segfin, const float* __restrict__ prodm,
    const float* __restrict__ params, float2* __restrict__ carries)
{
  int idx = blockIdx.x * 256 + threadIdx.x;   // 0..8191
  int b = idx >> 10, c = idx & 1023;
  float nu = expf(params[c]);
  float th = expf(params[H_ + c]);
  float mg = expf(-nu);
  float ltr = mg * cosf(th), lti = mg * sinf(th);
#pragma unroll
  for (int sq = 0; sq < 5; ++sq) {            // lambda^(2^5) = lambda^T, T=32
    float nr = ltr * ltr - lti * lti;
    float ni = 2.f * ltr * lti;
    ltr = nr; lti = ni;
  }
  float cr = 0.f, ci = 0.f;
  float2 fin = segfin[(size_t)(b * SEG_) * H_ + c];
  float pmv = prodm[b * SEG_];
  for (int s = 0; s < SEG_; ++s) {
    size_t o = (size_t)(b * SEG_ + s) * H_ + c;
    carries[o] = make_float2(cr, ci);
    float2 finn; float pmn;
    if (s + 1 < SEG_) { finn = segfin[o + H_]; pmn = prodm[b * SEG_ + s + 1]; }
    float nr = fin.x + pmv * (ltr * cr - lti * ci);
    float ni = fin.y + pmv * (ltr * ci + lti * cr);
    cr = nr; ci = ni;
    fin = finn; pmv = pmn;
  }
}

// ---------------------------------------------------------------------------
// Scan pass 3: full scan with injected carry, single h rewrite.
// ---------------------------------------------------------------------------
__global__ __launch_bounds__(256) void scan_full(
    u16* __restrict__ h, const float* __restrict__ mask,
    const float* __restrict__ params, const float2* __restrict__ carries)
{
  const int s = blockIdx.x, b = blockIdx.y;
  const int c4 = threadIdx.x * 4;
  float lr[4], li[4], sr[4], si[4];
#pragma unroll
  for (int j = 0; j < 4; ++j) {
    int c = c4 + j;
    float nu = expf(params[c]);
    float th = expf(params[H_ + c]);
    float mg = expf(-nu);
    lr[j] = mg * cosf(th);
    li[j] = mg * sinf(th);
    float2 cv = carries[(size_t)(b * SEG_ + s) * H_ + c];
    sr[j] = cv.x; si[j] = cv.y;
  }
  const int t0 = s * T_;
  u16* p = h + (size_t)(b * L_ + t0) * (2 * H_) + c4;
  const float* mp = mask + b * L_ + t0;
  float fac0;
  if (t0 == 0) fac0 = 0.f; else fac0 = mask[b * L_ + t0 - 1];

  ushort4 bre[2][8], bim[2][8];
#pragma unroll
  for (int j = 0; j < 8; ++j) {
    bre[0][j] = *(const ushort4*)(p + (size_t)j * 2 * H_);
    bim[0][j] = *(const ushort4*)(p + (size_t)j * 2 * H_ + H_);
  }
#pragma unroll
  for (int ch = 0; ch < T_ / 8; ++ch) {
    const int cur = ch & 1, nxt = cur ^ 1;
    if (ch < T_ / 8 - 1) {
      const u16* pn = p + (size_t)(ch + 1) * 8 * 2 * H_;
#pragma unroll
      for (int j = 0; j < 8; ++j) {
        bre[nxt][j] = *(const ushort4*)(pn + (size_t)j * 2 * H_);
        bim[nxt][j] = *(const ushort4*)(pn + (size_t)j * 2 * H_ + H_);
      }
    }
#pragma unroll
    for (int j = 0; j < 8; ++j) {
      int i = ch * 8 + j;
      float fac = (i == 0) ? fac0 : mp[i - 1];
      u16 rr[4], ii[4], orr[4], oii[4];
      *(ushort4*)rr = bre[cur][j]; *(ushort4*)ii = bim[cur][j];
#pragma unroll
      for (int k = 0; k < 4; ++k) {
        float ar = fac * sr[k], ai = fac * si[k];
        float nr2 = b2f(rr[k]) + lr[k] * ar - li[k] * ai;
        float ni2 = b2f(ii[k]) + lr[k] * ai + li[k] * ar;
        sr[k] = nr2; si[k] = ni2;
        orr[k] = f2b(nr2); oii[k] = f2b(ni2);
      }
      *(ushort4*)(p + (size_t)i * 2 * H_)      = *(ushort4*)orr;
      *(ushort4*)(p + (size_t)i * 2 * H_ + H_) = *(ushort4*)oii;
    }
  }
}

// ---------------------------------------------------------------------------
// LayerNorm: z = y + x; out = (z-mean)/sqrt(var+eps)*w + b.
// ---------------------------------------------------------------------------
__global__ __launch_bounds__(256) void ln_kernel(
    const float* __restrict__ y, const float* __restrict__ xg,
    const float* __restrict__ lnw, const float* __restrict__ lnb,
    float* __restrict__ out)
{
  const int wave = threadIdx.x >> 6, lane = threadIdx.x & 63;
  const size_t row = (size_t)blockIdx.x * 4 + wave;
  const float* yr = y + row * 512;
  const float* xr = xg + row * 512;
  float z[8];
  { float4 t = *(const float4*)&yr[lane * 4];        z[0]=t.x; z[1]=t.y; z[2]=t.z; z[3]=t.w; }
  { float4 t = *(const float4*)&yr[256 + lane * 4];  z[4]=t.x; z[5]=t.y; z[6]=t.z; z[7]=t.w; }
  { float4 t = *(const float4*)&xr[lane * 4];        z[0]+=t.x; z[1]+=t.y; z[2]+=t.z; z[3]+=t.w; }
  { float4 t = *(const float4*)&xr[256 + lane * 4];  z[4]+=t.x; z[5]+=t.y; z[6]+=t.z; z[7]+=t.w; }
  float s = 0.f, ss = 0.f;
#pragma unroll
  for (int j = 0; j < 8; ++j) { s += z[j]; ss += z[j] * z[j]; }
#pragma unroll
  for (int o = 32; o > 0; o >>= 1) { s += __shfl_xor(s, o); ss += __shfl_xor(ss, o); }
  const float mean = s * (1.f / 512.f);
  const float var  = ss * (1.f / 512.f) - mean * mean;
  const float inv  = rsqrtf(var + 1e-5f);
  float ov[8];
#pragma unroll
  for (int j = 0; j < 8; ++j) {
    int col = (j < 4) ? (lane * 4 + j) : (256 + lane * 4 + (j - 4));
    ov[j] = (z[j] - mean) * inv * lnw[col] + lnb[col];
  }
  { float4 t; t.x=ov[0]; t.y=ov[1]; t.z=ov[2]; t.w=ov[3];
    *(float4*)&out[row * 512 + lane * 4] = t; }
  { float4 t; t.x=ov[4]; t.y=ov[5]; t.z=ov[6]; t.w=ov[7];
    *(float4*)&out[row * 512 + 256 + lane * 4] = t; }
}

// ---------------------------------------------------------------------------
extern "C" void kernel_launch(void* const* d_in, const int* in_sizes, int n_in,
                              void* d_out, int out_size, void* d_ws, size_t ws_size,
                              hipStream_t stream) {
  (void)in_sizes; (void)n_in; (void)out_size; (void)ws_size;
  const float* x      = (const float*)d_in[0];
  const float* mask   = (const float*)d_in[1];
  const float* params = (const float*)d_in[2];   // [3][1024]: nu_log, theta_log, gamma_log
  const float* Wire   = (const float*)d_in[3];
  const float* Wiim   = (const float*)d_in[4];
  const float* bire   = (const float*)d_in[5];
  const float* biim   = (const float*)d_in[6];
  const float* Wore   = (const float*)d_in[7];
  const float* Woim   = (const float*)d_in[8];
  const float* bore   = (const float*)d_in[9];
  // d_in[10] = b_out_im: only affects Im(y), discarded by .real
  const float* lnw    = (const float*)d_in[11];
  const float* lnb    = (const float*)d_in[12];

  // Workspace (~105 MB). Region [0, 33.5M) time-shared:
  //   xb (gemm1 in) -> segfin[0,4M)+carries[4M,8M)+prodm[8M) -> y (gemm2/ln)
  char* ws = (char*)d_ws;
  u16*    xb      = (u16*)   (ws);                         // 16384*512*2 = 16.7M
  float2* segfin  = (float2*)(ws);                         // 8*64*1024*8 = 4M
  float2* carries = (float2*)(ws + (size_t)4194304);       // 4M
  float*  prodm   = (float*) (ws + (size_t)8388608);       // 2 KB
  float*  y       = (float*) (ws);                         // 16384*512*4 = 33.5M
  u16*    h       = (u16*)   (ws + (size_t)33554432);      // 16384*2048*2 = 67M
  u16*    winb    = (u16*)   (ws + (size_t)100663296);     // 2048*512*2 = 2M
  u16*    wcat    = (u16*)   (ws + (size_t)102760448);     // 512*2048*2 = 2M
  float*  bb      = (float*) (ws + (size_t)104857600);     // 2048*4 = 8 KB

  conv_f32_bf16<<<8192, 256, 0, stream>>>(x, xb, M_ * D_ / 4);
  prep_weights<<<2048, 256, 0, stream>>>(Wire, Wiim, Wore, Woim, bire, biim,
                                         params, winb, wcat, bb);

  // h[re|im] = x @ (gamma*[W_in_re;W_in_im])^T + bb  (M=16384,N=2048,K=512)
  gemm1_256<<<dim3(64, 16), 256, 0, stream>>>(
      xb, winb, 512, h, 2048, bb);

  scan_fin<<<dim3(SEG_, B_), 256, 0, stream>>>(h, mask, params, segfin, prodm);
  scan_carry<<<32, 256, 0, stream>>>(segfin, prodm, params, carries);
  scan_full<<<dim3(SEG_, B_), 256, 0, stream>>>(h, mask, params, carries);

  // y = h_cat @ Wcat^T + b_out_re   (M=16384,N=512,K=2048), fp32 out
  gemm_bt<<<dim3(128, 4), 256, 0, stream>>>(
      h, wcat, 2048, y, 512, bore);

  ln_kernel<<<4096, 256, 0, stream>>>(y, x, lnw, lnb, (float*)d_out);
}